// Round 2
// baseline (243.551 us; speedup 1.0000x reference)
//
#include <hip/hip_runtime.h>
#include <hip/hip_bf16.h>

#define N_ENT 100000
#define NB 16
#define DIM 128
#define NSHARD 8

// ---------------- kernel 1: head = normalize(ent[e1]) + normalize(rel[r]) ----
__global__ __launch_bounds__(128) void head_kernel(
    const int* __restrict__ e1, const int* __restrict__ rel,
    const float* __restrict__ ent, const float* __restrict__ relemb,
    float* __restrict__ head)
{
    int b = blockIdx.x, d = threadIdx.x;
    float ev = ent[e1[b] * DIM + d];
    float rv = relemb[rel[b] * DIM + d];
    __shared__ float s1[DIM], s2[DIM];
    s1[d] = ev * ev;
    s2[d] = rv * rv;
    __syncthreads();
    for (int s = 64; s > 0; s >>= 1) {
        if (d < s) { s1[d] += s1[d + s]; s2[d] += s2[d + s]; }
        __syncthreads();
    }
    float ne = fmaxf(sqrtf(s1[0]), 1e-12f);
    float nr = fmaxf(sqrtf(s2[0]), 1e-12f);
    head[b * DIM + d] = ev / ne + rv / nr;
}

// ---------------- kernel 2: fused dist + exp + sharded row sums -------------
// One thread per entity. acc[16] in VGPRs. head reads are wave-uniform ->
// expected to scalarize to s_load_dwordx4 (scalar pipe, free vs VALU).
// No max-subtraction needed: dist <= sqrt(128)*(||h||+||n||) <= 34, exp(34)
// ~ 5.8e14, sum < 6e19 -- comfortably inside fp32 range.
__global__ __launch_bounds__(64) void dist_kernel(
    const float* __restrict__ ent, const float* __restrict__ head,
    float* __restrict__ shards, float* __restrict__ out)
{
    const int tid = threadIdx.x;
    const int n = blockIdx.x * 64 + tid;
    const bool valid = (n < N_ENT);
    const int nc = valid ? n : (N_ENT - 1);

    const float4* __restrict__ row = (const float4*)&ent[nc * DIM];
    const float4* __restrict__ hg  = (const float4*)head;

    // pass 1: squared norm of the entity row (streams the row through L1)
    float s = 0.f;
    #pragma unroll
    for (int j = 0; j < DIM / 4; j++) {
        float4 v = row[j];
        s = fmaf(v.x, v.x, s); s = fmaf(v.y, v.y, s);
        s = fmaf(v.z, v.z, s); s = fmaf(v.w, v.w, s);
    }
    const float inv = 1.0f / fmaxf(sqrtf(s), 1e-12f);

    float acc[NB];
    #pragma unroll
    for (int b = 0; b < NB; b++) acc[b] = 0.f;

    // pass 2: L1 distances to all 16 heads (row re-read hits L1/L2)
    #pragma unroll 4
    for (int j = 0; j < DIM / 4; j++) {
        float4 v = row[j];
        #pragma unroll
        for (int b = 0; b < NB; b++) {
            float4 h = hg[b * (DIM / 4) + j];   // uniform address -> s_load
            acc[b] += fabsf(fmaf(-v.x, inv, h.x)) + fabsf(fmaf(-v.y, inv, h.y))
                    + fabsf(fmaf(-v.z, inv, h.z)) + fabsf(fmaf(-v.w, inv, h.w));
        }
    }

    // exp, store, wave-reduce, sharded atomic row-sum
    float* shard = &shards[(blockIdx.x & (NSHARD - 1)) * NB];
    #pragma unroll
    for (int b = 0; b < NB; b++) {
        float e = valid ? expf(acc[b]) : 0.f;
        if (valid) out[b * N_ENT + n] = e;
        e += __shfl_down(e, 32);
        e += __shfl_down(e, 16);
        e += __shfl_down(e, 8);
        e += __shfl_down(e, 4);
        e += __shfl_down(e, 2);
        e += __shfl_down(e, 1);
        if (tid == 0) atomicAdd(&shard[b], e);
    }
}

// ---------------- kernel 3: out *= 1/rowsum[b] ------------------------------
__global__ __launch_bounds__(256) void scale_kernel(
    float* __restrict__ out, const float* __restrict__ shards)
{
    const int b = blockIdx.y;
    float S = 0.f;
    #pragma unroll
    for (int s = 0; s < NSHARD; s++) S += shards[s * NB + b];
    const float invS = 1.0f / S;
    const int i = blockIdx.x * 256 + threadIdx.x;      // float4 index
    if (i < N_ENT / 4) {
        float4* row = (float4*)&out[b * N_ENT];
        float4 v = row[i];
        v.x *= invS; v.y *= invS; v.z *= invS; v.w *= invS;
        row[i] = v;
    }
}

extern "C" void kernel_launch(void* const* d_in, const int* in_sizes, int n_in,
                              void* d_out, int out_size, void* d_ws, size_t ws_size,
                              hipStream_t stream) {
    const int*   e1     = (const int*)d_in[0];
    const int*   rel    = (const int*)d_in[1];
    const float* ent    = (const float*)d_in[4];
    const float* relemb = (const float*)d_in[5];
    float* out = (float*)d_out;

    float* head   = (float*)d_ws;                       // 16*128 f32 = 8192 B
    float* shards = (float*)((char*)d_ws + 8192);       // 8*16 f32 = 512 B

    // shards are poisoned 0xAA before every timed launch -> zero them
    hipMemsetAsync((char*)d_ws + 8192, 0, NSHARD * NB * sizeof(float), stream);

    head_kernel<<<16, 128, 0, stream>>>(e1, rel, ent, relemb, head);

    const int nblk = (N_ENT + 63) / 64;   // 1563
    dist_kernel<<<nblk, 64, 0, stream>>>(ent, head, shards, out);

    scale_kernel<<<dim3((N_ENT / 4 + 255) / 256, NB), 256, 0, stream>>>(out, shards);
}

// Round 3
// 201.381 us; speedup vs baseline: 1.2094x; 1.2094x over previous
//
#include <hip/hip_runtime.h>
#include <hip/hip_bf16.h>

#define N_ENT 100000
#define NB 16
#define DIM 128
#define TILE 64
#define RSTRIDE 132      // 128+4: pads per-lane row reads across all 8 bank groups
#define NSHARD 8

// ---------------- kernel 1: head = normalize(ent[e1]) + normalize(rel[r]) ----
__global__ __launch_bounds__(128) void head_kernel(
    const int* __restrict__ e1, const int* __restrict__ rel,
    const float* __restrict__ ent, const float* __restrict__ relemb,
    float* __restrict__ head)
{
    int b = blockIdx.x, d = threadIdx.x;
    float ev = ent[e1[b] * DIM + d];
    float rv = relemb[rel[b] * DIM + d];
    __shared__ float s1[DIM], s2[DIM];
    s1[d] = ev * ev;
    s2[d] = rv * rv;
    __syncthreads();
    for (int s = 64; s > 0; s >>= 1) {
        if (d < s) { s1[d] += s1[d + s]; s2[d] += s2[d + s]; }
        __syncthreads();
    }
    float ne = fmaxf(sqrtf(s1[0]), 1e-12f);
    float nr = fmaxf(sqrtf(s2[0]), 1e-12f);
    head[b * DIM + d] = ev / ne + rv / nr;
}

// ---------------- kernel 2: fused dist + exp + sharded row sums -------------
// Block = 256 thr = 4 waves over a 64-entity tile. Wave w computes b in
// [4w,4w+4) for all 64 entities (lane = entity). Both operands in LDS:
// rows padded (stride 132) for conflict-free per-lane b128 reads, heads
// read at wave-uniform addresses (broadcast, conflict-free).
__global__ __launch_bounds__(256) void dist_kernel(
    const float* __restrict__ ent, const float* __restrict__ head,
    float* __restrict__ shards, float* __restrict__ out)
{
    __shared__ float ldsRow[TILE * RSTRIDE];   // 33792 B
    __shared__ float ldsHead[NB * DIM];        // 8192 B
    __shared__ float ldsInv[TILE];

    const int tid  = threadIdx.x;
    const int lane = tid & 63;
    const int wv   = tid >> 6;                 // 0..3 -> b group
    const int n0   = blockIdx.x * TILE;

    // stage heads (512 float4, 2 per thread)
    {
        const float4* hg = (const float4*)head;
        float4* hl = (float4*)ldsHead;
        hl[tid]       = hg[tid];
        hl[tid + 256] = hg[tid + 256];
    }
    // stage rows: 2048 float4, 8 per thread, coalesced global, padded LDS
    {
        const float4* eg = (const float4*)ent;
        #pragma unroll
        for (int i = 0; i < 8; i++) {
            int g = tid + i * 256;             // float4 index within tile
            int r = g >> 5, c = g & 31;
            int gr = n0 + r;
            if (gr >= N_ENT) gr = N_ENT - 1;   // clamp for the partial last tile
            float4 v = eg[gr * (DIM / 4) + c];
            *(float4*)&ldsRow[r * RSTRIDE + c * 4] = v;
        }
    }
    __syncthreads();

    // cooperative row norms: 4 threads per row, 32 floats each
    {
        int r = tid >> 2, q = tid & 3;
        const float* p = &ldsRow[r * RSTRIDE + q * 32];
        float s = 0.f;
        #pragma unroll
        for (int k = 0; k < 8; k++) {
            float4 v = *(const float4*)&p[k * 4];
            s = fmaf(v.x, v.x, s); s = fmaf(v.y, v.y, s);
            s = fmaf(v.z, v.z, s); s = fmaf(v.w, v.w, s);
        }
        s += __shfl_down(s, 2);
        s += __shfl_down(s, 1);
        if (q == 0) ldsInv[r] = 1.0f / fmaxf(sqrtf(s), 1e-12f);
    }
    __syncthreads();

    const float inv = ldsInv[lane];
    const float* rp = &ldsRow[lane * RSTRIDE];
    const float4* h0 = (const float4*)&ldsHead[(wv * 4 + 0) * DIM];
    const float4* h1 = (const float4*)&ldsHead[(wv * 4 + 1) * DIM];
    const float4* h2 = (const float4*)&ldsHead[(wv * 4 + 2) * DIM];
    const float4* h3 = (const float4*)&ldsHead[(wv * 4 + 3) * DIM];

    float a0 = 0.f, a1 = 0.f, a2 = 0.f, a3 = 0.f;
    #pragma unroll 4
    for (int j = 0; j < DIM / 4; j++) {
        float4 v  = *(const float4*)&rp[j * 4];
        float4 q0 = h0[j], q1 = h1[j], q2 = h2[j], q3 = h3[j];
        a0 += fabsf(fmaf(-v.x, inv, q0.x)) + fabsf(fmaf(-v.y, inv, q0.y))
            + fabsf(fmaf(-v.z, inv, q0.z)) + fabsf(fmaf(-v.w, inv, q0.w));
        a1 += fabsf(fmaf(-v.x, inv, q1.x)) + fabsf(fmaf(-v.y, inv, q1.y))
            + fabsf(fmaf(-v.z, inv, q1.z)) + fabsf(fmaf(-v.w, inv, q1.w));
        a2 += fabsf(fmaf(-v.x, inv, q2.x)) + fabsf(fmaf(-v.y, inv, q2.y))
            + fabsf(fmaf(-v.z, inv, q2.z)) + fabsf(fmaf(-v.w, inv, q2.w));
        a3 += fabsf(fmaf(-v.x, inv, q3.x)) + fabsf(fmaf(-v.y, inv, q3.y))
            + fabsf(fmaf(-v.z, inv, q3.z)) + fabsf(fmaf(-v.w, inv, q3.w));
    }

    // exp (no max-subtract needed: dist <= 34, exp fits fp32 easily)
    const int n = n0 + lane;
    const bool valid = (n < N_ENT);
    const int bbase = wv * 4;
    float e0 = valid ? __expf(a0) : 0.f;
    float e1 = valid ? __expf(a1) : 0.f;
    float e2 = valid ? __expf(a2) : 0.f;
    float e3 = valid ? __expf(a3) : 0.f;
    if (valid) {
        out[(bbase + 0) * N_ENT + n] = e0;   // lane-contiguous: coalesced
        out[(bbase + 1) * N_ENT + n] = e1;
        out[(bbase + 2) * N_ENT + n] = e2;
        out[(bbase + 3) * N_ENT + n] = e3;
    }

#define WRED(x) { x += __shfl_down(x, 32); x += __shfl_down(x, 16); \
                  x += __shfl_down(x, 8);  x += __shfl_down(x, 4);  \
                  x += __shfl_down(x, 2);  x += __shfl_down(x, 1); }
    WRED(e0) WRED(e1) WRED(e2) WRED(e3)
#undef WRED
    if (lane == 0) {
        float* sh = &shards[(blockIdx.x & (NSHARD - 1)) * NB + bbase];
        atomicAdd(&sh[0], e0);
        atomicAdd(&sh[1], e1);
        atomicAdd(&sh[2], e2);
        atomicAdd(&sh[3], e3);
    }
}

// ---------------- kernel 3: out *= 1/rowsum[b] ------------------------------
__global__ __launch_bounds__(256) void scale_kernel(
    float* __restrict__ out, const float* __restrict__ shards)
{
    const int b = blockIdx.y;
    float S = 0.f;
    #pragma unroll
    for (int s = 0; s < NSHARD; s++) S += shards[s * NB + b];
    const float invS = 1.0f / S;
    const int i = blockIdx.x * 256 + threadIdx.x;      // float4 index
    if (i < N_ENT / 4) {
        float4* row = (float4*)&out[b * N_ENT];
        float4 v = row[i];
        v.x *= invS; v.y *= invS; v.z *= invS; v.w *= invS;
        row[i] = v;
    }
}

extern "C" void kernel_launch(void* const* d_in, const int* in_sizes, int n_in,
                              void* d_out, int out_size, void* d_ws, size_t ws_size,
                              hipStream_t stream) {
    const int*   e1     = (const int*)d_in[0];
    const int*   rel    = (const int*)d_in[1];
    const float* ent    = (const float*)d_in[4];
    const float* relemb = (const float*)d_in[5];
    float* out = (float*)d_out;

    float* head   = (float*)d_ws;                       // 16*128 f32 = 8192 B
    float* shards = (float*)((char*)d_ws + 8192);       // 8*16 f32 = 512 B

    // shards are poisoned 0xAA before every timed launch -> zero them
    hipMemsetAsync((char*)d_ws + 8192, 0, NSHARD * NB * sizeof(float), stream);

    head_kernel<<<16, 128, 0, stream>>>(e1, rel, ent, relemb, head);

    const int ntile = (N_ENT + TILE - 1) / TILE;        // 1563
    dist_kernel<<<ntile, 256, 0, stream>>>(ent, head, shards, out);

    scale_kernel<<<dim3((N_ENT / 4 + 255) / 256, NB), 256, 0, stream>>>(out, shards);
}

// Round 4
// 121.674 us; speedup vs baseline: 2.0017x; 1.6551x over previous
//
#include <hip/hip_runtime.h>
#include <hip/hip_bf16.h>

#define N_ENT 100000
#define NB 16
#define DIM 128
#define TILE 64
#define RSTRIDE 132      // 128+4 floats: b128 reads cover all 32 banks per 8-lane phase
#define NBLK 768         // 3 blocks/CU * 256 CU
#define N_TILES ((N_ENT + TILE - 1) / TILE)   // 1563

// ---------------- kernel 1: head = normalize(ent[e1]) + normalize(rel[r]) ----
__global__ __launch_bounds__(128) void head_kernel(
    const int* __restrict__ e1, const int* __restrict__ rel,
    const float* __restrict__ ent, const float* __restrict__ relemb,
    float* __restrict__ head)
{
    int b = blockIdx.x, d = threadIdx.x;
    float ev = ent[e1[b] * DIM + d];
    float rv = relemb[rel[b] * DIM + d];
    __shared__ float s1[DIM], s2[DIM];
    s1[d] = ev * ev;
    s2[d] = rv * rv;
    __syncthreads();
    for (int s = 64; s > 0; s >>= 1) {
        if (d < s) { s1[d] += s1[d + s]; s2[d] += s2[d + s]; }
        __syncthreads();
    }
    float ne = fmaxf(sqrtf(s1[0]), 1e-12f);
    float nr = fmaxf(sqrtf(s2[0]), 1e-12f);
    head[b * DIM + d] = ev / ne + rv / nr;
}

// ---------------- kernel 2: fused dist + exp, NO atomics --------------------
// 768 persistent blocks grid-stride over 1563 tiles. Block = 4 waves; wave w
// computes b in [4w,4w+4) for the tile's 64 entities (lane = entity).
// exp-sums accumulate per-lane in registers across tiles; one shuffle-reduce
// at the end writes 16 floats into a private partials[b][block] slot.
__global__ __launch_bounds__(256) void dist_kernel(
    const float* __restrict__ ent, const float* __restrict__ head,
    float* __restrict__ partials, float* __restrict__ out)
{
    __shared__ float ldsRow[TILE * RSTRIDE];   // 33792 B
    __shared__ float ldsHead[NB * DIM];        // 8192 B
    __shared__ float ldsInv[TILE];

    const int tid  = threadIdx.x;
    const int lane = tid & 63;
    const int wv   = tid >> 6;                 // 0..3 -> b group
    const int bbase = wv * 4;

    // stage heads once (512 float4, 2 per thread)
    {
        const float4* hg = (const float4*)head;
        float4* hl = (float4*)ldsHead;
        hl[tid]       = hg[tid];
        hl[tid + 256] = hg[tid + 256];
    }

    float es0 = 0.f, es1 = 0.f, es2 = 0.f, es3 = 0.f;  // per-lane exp sums

    for (int tile = blockIdx.x; tile < N_TILES; tile += NBLK) {
        const int n0 = tile * TILE;
        __syncthreads();   // prev-tile compute done (and head staging, iter 0)

        // stage rows: 2048 float4, 8 per thread, coalesced global, padded LDS
        {
            const float4* eg = (const float4*)ent;
            #pragma unroll
            for (int i = 0; i < 8; i++) {
                int g = tid + i * 256;             // float4 index within tile
                int r = g >> 5, c = g & 31;
                int gr = n0 + r;
                if (gr >= N_ENT) gr = N_ENT - 1;   // clamp for partial last tile
                float4 v = eg[gr * (DIM / 4) + c];
                *(float4*)&ldsRow[r * RSTRIDE + c * 4] = v;
            }
        }
        __syncthreads();

        // cooperative row norms: 4 threads per row, 32 floats each
        {
            int r = tid >> 2, q = tid & 3;
            const float* p = &ldsRow[r * RSTRIDE + q * 32];
            float s = 0.f;
            #pragma unroll
            for (int k = 0; k < 8; k++) {
                float4 v = *(const float4*)&p[k * 4];
                s = fmaf(v.x, v.x, s); s = fmaf(v.y, v.y, s);
                s = fmaf(v.z, v.z, s); s = fmaf(v.w, v.w, s);
            }
            s += __shfl_down(s, 2);
            s += __shfl_down(s, 1);
            if (q == 0) ldsInv[r] = 1.0f / fmaxf(sqrtf(s), 1e-12f);
        }
        __syncthreads();

        const float inv = ldsInv[lane];
        const float* rp = &ldsRow[lane * RSTRIDE];
        const float4* h0 = (const float4*)&ldsHead[(bbase + 0) * DIM];
        const float4* h1 = (const float4*)&ldsHead[(bbase + 1) * DIM];
        const float4* h2 = (const float4*)&ldsHead[(bbase + 2) * DIM];
        const float4* h3 = (const float4*)&ldsHead[(bbase + 3) * DIM];

        float a0 = 0.f, a1 = 0.f, a2 = 0.f, a3 = 0.f;
        #pragma unroll 4
        for (int j = 0; j < DIM / 4; j++) {
            float4 v  = *(const float4*)&rp[j * 4];
            float4 q0 = h0[j], q1 = h1[j], q2 = h2[j], q3 = h3[j];
            a0 += fabsf(fmaf(-v.x, inv, q0.x)) + fabsf(fmaf(-v.y, inv, q0.y))
                + fabsf(fmaf(-v.z, inv, q0.z)) + fabsf(fmaf(-v.w, inv, q0.w));
            a1 += fabsf(fmaf(-v.x, inv, q1.x)) + fabsf(fmaf(-v.y, inv, q1.y))
                + fabsf(fmaf(-v.z, inv, q1.z)) + fabsf(fmaf(-v.w, inv, q1.w));
            a2 += fabsf(fmaf(-v.x, inv, q2.x)) + fabsf(fmaf(-v.y, inv, q2.y))
                + fabsf(fmaf(-v.z, inv, q2.z)) + fabsf(fmaf(-v.w, inv, q2.w));
            a3 += fabsf(fmaf(-v.x, inv, q3.x)) + fabsf(fmaf(-v.y, inv, q3.y))
                + fabsf(fmaf(-v.z, inv, q3.z)) + fabsf(fmaf(-v.w, inv, q3.w));
        }

        // exp; no max-subtract needed: dist <= 34, sums < 6e19 << fp32 max
        const int n = n0 + lane;
        const bool valid = (n < N_ENT);
        float e0 = valid ? __expf(a0) : 0.f;
        float e1 = valid ? __expf(a1) : 0.f;
        float e2 = valid ? __expf(a2) : 0.f;
        float e3 = valid ? __expf(a3) : 0.f;
        if (valid) {
            out[(bbase + 0) * N_ENT + n] = e0;   // lane-contiguous: coalesced
            out[(bbase + 1) * N_ENT + n] = e1;
            out[(bbase + 2) * N_ENT + n] = e2;
            out[(bbase + 3) * N_ENT + n] = e3;
        }
        es0 += e0; es1 += e1; es2 += e2; es3 += e3;
    }

#define WRED(x) { x += __shfl_down(x, 32); x += __shfl_down(x, 16); \
                  x += __shfl_down(x, 8);  x += __shfl_down(x, 4);  \
                  x += __shfl_down(x, 2);  x += __shfl_down(x, 1); }
    WRED(es0) WRED(es1) WRED(es2) WRED(es3)
#undef WRED
    if (lane == 0) {   // b-major: partials[b*NBLK + block] — no contention
        partials[(bbase + 0) * NBLK + blockIdx.x] = es0;
        partials[(bbase + 1) * NBLK + blockIdx.x] = es1;
        partials[(bbase + 2) * NBLK + blockIdx.x] = es2;
        partials[(bbase + 3) * NBLK + blockIdx.x] = es3;
    }
}

// ---------------- kernel 3: rowsum[b] = sum over blocks of partials[b][*] ---
__global__ __launch_bounds__(64) void reduce_kernel(
    const float* __restrict__ partials, float* __restrict__ rowsum)
{
    const int b = blockIdx.x;
    const int lane = threadIdx.x;
    float s = 0.f;
    for (int k = lane; k < NBLK; k += 64) s += partials[b * NBLK + k];
    s += __shfl_down(s, 32); s += __shfl_down(s, 16);
    s += __shfl_down(s, 8);  s += __shfl_down(s, 4);
    s += __shfl_down(s, 2);  s += __shfl_down(s, 1);
    if (lane == 0) rowsum[b] = s;
}

// ---------------- kernel 4: out *= 1/rowsum[b] ------------------------------
__global__ __launch_bounds__(256) void scale_kernel(
    float* __restrict__ out, const float* __restrict__ rowsum)
{
    const int b = blockIdx.y;
    const float invS = 1.0f / rowsum[b];
    const int i = blockIdx.x * 256 + threadIdx.x;      // float4 index
    if (i < N_ENT / 4) {
        float4* row = (float4*)&out[b * N_ENT];
        float4 v = row[i];
        v.x *= invS; v.y *= invS; v.z *= invS; v.w *= invS;
        row[i] = v;
    }
}

extern "C" void kernel_launch(void* const* d_in, const int* in_sizes, int n_in,
                              void* d_out, int out_size, void* d_ws, size_t ws_size,
                              hipStream_t stream) {
    const int*   e1     = (const int*)d_in[0];
    const int*   rel    = (const int*)d_in[1];
    const float* ent    = (const float*)d_in[4];
    const float* relemb = (const float*)d_in[5];
    float* out = (float*)d_out;

    float* head     = (float*)d_ws;                         // 16*128 f32
    float* partials = (float*)((char*)d_ws + 8192);         // 16*768 f32 = 49152 B
    float* rowsum   = (float*)((char*)d_ws + 8192 + 49152); // 16 f32
    // every partials/rowsum slot is written before it is read -> no zeroing

    head_kernel<<<16, 128, 0, stream>>>(e1, rel, ent, relemb, head);
    dist_kernel<<<NBLK, 256, 0, stream>>>(ent, head, partials, out);
    reduce_kernel<<<NB, 64, 0, stream>>>(partials, rowsum);
    scale_kernel<<<dim3((N_ENT / 4 + 255) / 256, NB), 256, 0, stream>>>(out, rowsum);
}

// Round 5
// 113.345 us; speedup vs baseline: 2.1488x; 1.0735x over previous
//
#include <hip/hip_runtime.h>
#include <hip/hip_bf16.h>

#define N_ENT 100000
#define NB 16
#define DIM 128
#define TILE 64
#define RSTRIDE 132      // 128+4 floats: per-lane b128 reads conflict-free
#define NBLK 1024        // 4 blocks/CU * 256 CU (LDS 34KB -> 4/CU)
#define N_TILES ((N_ENT + TILE - 1) / TILE)   // 1563

// ---------------- kernel 1: head = normalize(ent[e1]) + normalize(rel[r]) ----
__global__ __launch_bounds__(128) void head_kernel(
    const int* __restrict__ e1, const int* __restrict__ rel,
    const float* __restrict__ ent, const float* __restrict__ relemb,
    float* __restrict__ head)
{
    int b = blockIdx.x, d = threadIdx.x;
    float ev = ent[e1[b] * DIM + d];
    float rv = relemb[rel[b] * DIM + d];
    __shared__ float s1[DIM], s2[DIM];
    s1[d] = ev * ev;
    s2[d] = rv * rv;
    __syncthreads();
    for (int s = 64; s > 0; s >>= 1) {
        if (d < s) { s1[d] += s1[d + s]; s2[d] += s2[d + s]; }
        __syncthreads();
    }
    float ne = fmaxf(sqrtf(s1[0]), 1e-12f);
    float nr = fmaxf(sqrtf(s2[0]), 1e-12f);
    head[b * DIM + d] = ev / ne + rv / nr;
}

// ---------------- kernel 2: fused dist + exp, no atomics --------------------
// 1024 blocks grid-stride over 1563 tiles (critical path = 2 tiles). Block =
// 4 waves; wave w computes b in [4w,4w+4) for the tile's 64 entities
// (lane = entity). Rows staged in padded LDS; heads read from GLOBAL at
// wave-uniform addresses (wv via readfirstlane -> provably uniform ->
// s_load_dwordx4 on the scalar pipe, K$-resident). This removes the 512
// broadcast ds_read_b128 per block-tile that dominated round 4's LDS pipe.
__global__ __launch_bounds__(256) void dist_kernel(
    const float* __restrict__ ent, const float* __restrict__ head,
    float* __restrict__ partials, float* __restrict__ out)
{
    __shared__ float ldsRow[TILE * RSTRIDE];   // 33792 B
    __shared__ float ldsInv[TILE];             // 256 B

    const int tid  = threadIdx.x;
    const int lane = tid & 63;
    const int wv   = __builtin_amdgcn_readfirstlane(tid >> 6);  // uniform 0..3
    const int bbase = wv * 4;
    const float4* __restrict__ hg = (const float4*)head;  // uniform-indexed

    float es0 = 0.f, es1 = 0.f, es2 = 0.f, es3 = 0.f;  // per-lane exp sums

    for (int tile = blockIdx.x; tile < N_TILES; tile += NBLK) {
        const int n0 = tile * TILE;
        __syncthreads();   // prev-tile LDS reuse guard

        // stage rows: 2048 float4, 8 per thread, coalesced global, padded LDS
        {
            const float4* eg = (const float4*)ent;
            #pragma unroll
            for (int i = 0; i < 8; i++) {
                int g = tid + i * 256;             // float4 index within tile
                int r = g >> 5, c = g & 31;
                int gr = n0 + r;
                if (gr >= N_ENT) gr = N_ENT - 1;   // clamp for partial last tile
                float4 v = eg[gr * (DIM / 4) + c];
                *(float4*)&ldsRow[r * RSTRIDE + c * 4] = v;
            }
        }
        __syncthreads();

        // cooperative row norms: 4 threads per row, 32 floats each
        {
            int r = tid >> 2, q = tid & 3;
            const float* p = &ldsRow[r * RSTRIDE + q * 32];
            float s = 0.f;
            #pragma unroll
            for (int k = 0; k < 8; k++) {
                float4 v = *(const float4*)&p[k * 4];
                s = fmaf(v.x, v.x, s); s = fmaf(v.y, v.y, s);
                s = fmaf(v.z, v.z, s); s = fmaf(v.w, v.w, s);
            }
            s += __shfl_down(s, 2);
            s += __shfl_down(s, 1);
            if (q == 0) ldsInv[r] = 1.0f / fmaxf(sqrtf(s), 1e-12f);
        }
        __syncthreads();

        const float inv = ldsInv[lane];
        const float* rp = &ldsRow[lane * RSTRIDE];

        float a0 = 0.f, a1 = 0.f, a2 = 0.f, a3 = 0.f;
        #pragma unroll 8
        for (int j = 0; j < DIM / 4; j++) {
            float4 v  = *(const float4*)&rp[j * 4];
            float4 q0 = hg[(bbase + 0) * (DIM / 4) + j];   // uniform -> s_load
            float4 q1 = hg[(bbase + 1) * (DIM / 4) + j];
            float4 q2 = hg[(bbase + 2) * (DIM / 4) + j];
            float4 q3 = hg[(bbase + 3) * (DIM / 4) + j];
            a0 += fabsf(fmaf(-v.x, inv, q0.x)) + fabsf(fmaf(-v.y, inv, q0.y))
                + fabsf(fmaf(-v.z, inv, q0.z)) + fabsf(fmaf(-v.w, inv, q0.w));
            a1 += fabsf(fmaf(-v.x, inv, q1.x)) + fabsf(fmaf(-v.y, inv, q1.y))
                + fabsf(fmaf(-v.z, inv, q1.z)) + fabsf(fmaf(-v.w, inv, q1.w));
            a2 += fabsf(fmaf(-v.x, inv, q2.x)) + fabsf(fmaf(-v.y, inv, q2.y))
                + fabsf(fmaf(-v.z, inv, q2.z)) + fabsf(fmaf(-v.w, inv, q2.w));
            a3 += fabsf(fmaf(-v.x, inv, q3.x)) + fabsf(fmaf(-v.y, inv, q3.y))
                + fabsf(fmaf(-v.z, inv, q3.z)) + fabsf(fmaf(-v.w, inv, q3.w));
        }

        // exp; no max-subtract needed: dist <= 34, sums < 6e19 << fp32 max
        const int n = n0 + lane;
        const bool valid = (n < N_ENT);
        float e0 = valid ? __expf(a0) : 0.f;
        float e1 = valid ? __expf(a1) : 0.f;
        float e2 = valid ? __expf(a2) : 0.f;
        float e3 = valid ? __expf(a3) : 0.f;
        if (valid) {
            out[(bbase + 0) * N_ENT + n] = e0;   // lane-contiguous: coalesced
            out[(bbase + 1) * N_ENT + n] = e1;
            out[(bbase + 2) * N_ENT + n] = e2;
            out[(bbase + 3) * N_ENT + n] = e3;
        }
        es0 += e0; es1 += e1; es2 += e2; es3 += e3;
    }

#define WRED(x) { x += __shfl_down(x, 32); x += __shfl_down(x, 16); \
                  x += __shfl_down(x, 8);  x += __shfl_down(x, 4);  \
                  x += __shfl_down(x, 2);  x += __shfl_down(x, 1); }
    WRED(es0) WRED(es1) WRED(es2) WRED(es3)
#undef WRED
    if (lane == 0) {   // b-major: partials[b*NBLK + block] — no contention
        partials[(bbase + 0) * NBLK + blockIdx.x] = es0;
        partials[(bbase + 1) * NBLK + blockIdx.x] = es1;
        partials[(bbase + 2) * NBLK + blockIdx.x] = es2;
        partials[(bbase + 3) * NBLK + blockIdx.x] = es3;
    }
}

// ---------------- kernel 3: out *= 1/sum(partials[b][*]) --------------------
// Each block redundantly reduces its row's 1024 partials (L2-hit, ~4 loads
// per thread) — saves a separate reduce kernel launch.
__global__ __launch_bounds__(256) void scale_kernel(
    float* __restrict__ out, const float* __restrict__ partials)
{
    const int b = blockIdx.y;
    const int tid = threadIdx.x;

    // load my output chunk first (overlaps with the reduction)
    const int i = blockIdx.x * 256 + tid;              // float4 index
    float4 v = make_float4(0.f, 0.f, 0.f, 0.f);
    float4* row = (float4*)&out[b * N_ENT];
    const bool valid = (i < N_ENT / 4);
    if (valid) v = row[i];

    float s = 0.f;
    #pragma unroll
    for (int k = 0; k < NBLK / 256; k++) s += partials[b * NBLK + k * 256 + tid];
    s += __shfl_down(s, 32); s += __shfl_down(s, 16);
    s += __shfl_down(s, 8);  s += __shfl_down(s, 4);
    s += __shfl_down(s, 2);  s += __shfl_down(s, 1);
    __shared__ float red[4];
    if ((tid & 63) == 0) red[tid >> 6] = s;
    __syncthreads();
    const float invS = 1.0f / (red[0] + red[1] + red[2] + red[3]);

    if (valid) {
        v.x *= invS; v.y *= invS; v.z *= invS; v.w *= invS;
        row[i] = v;
    }
}

extern "C" void kernel_launch(void* const* d_in, const int* in_sizes, int n_in,
                              void* d_out, int out_size, void* d_ws, size_t ws_size,
                              hipStream_t stream) {
    const int*   e1     = (const int*)d_in[0];
    const int*   rel    = (const int*)d_in[1];
    const float* ent    = (const float*)d_in[4];
    const float* relemb = (const float*)d_in[5];
    float* out = (float*)d_out;

    float* head     = (float*)d_ws;                    // 16*128 f32 = 8192 B
    float* partials = (float*)((char*)d_ws + 8192);    // 16*1024 f32 = 65536 B
    // every partials slot is written before it is read -> no zeroing needed

    head_kernel<<<16, 128, 0, stream>>>(e1, rel, ent, relemb, head);
    dist_kernel<<<NBLK, 256, 0, stream>>>(ent, head, partials, out);
    scale_kernel<<<dim3((N_ENT / 4 + 255) / 256, NB), 256, 0, stream>>>(out, partials);
}